// Round 5
// baseline (397.806 us; speedup 1.0000x reference)
//
#include <hip/hip_runtime.h>

// ---------------------------------------------------------------------------
// GCN model, re-associated: per layer h = relu((A_hat @ h_prev) @ W^T + b);
// pool BEFORE gcn_out linear. Node features BF16 (fp32 accumulate).
// dinv folded into features: h' = dinv*h, so y[n] = dinv[n]*(sum h'[src] +
// h'[n]) -- no per-edge weights; CSR entries are 2B src indices.
// CSR built via bucketed two-phase binning for dense write locality.
// ---------------------------------------------------------------------------

typedef __attribute__((ext_vector_type(8))) short short8;   // MFMA A/B frag
typedef __attribute__((ext_vector_type(4))) float f32x4;    // MFMA C/D frag

#define BKT 64        // nodes per bucket
#define SL 8          // XCD slices
#define NBINBLK 256   // k_hist / k_bin grid (must match)

__device__ __forceinline__ unsigned short f2bf(float f) {
    union { float f; unsigned u; } c; c.f = f;
    unsigned u = c.u;
    unsigned r = u + 0x7FFFu + ((u >> 16) & 1u);   // RNE
    return (unsigned short)(r >> 16);
}
__device__ __forceinline__ float bflo(unsigned w) {
    union { unsigned u; float f; } c; c.u = w << 16; return c.f;
}
__device__ __forceinline__ float bfhi(unsigned w) {
    union { unsigned u; float f; } c; c.u = w & 0xFFFF0000u; return c.f;
}

__global__ void k_zero(int* ghist, float* pool, float* cnt, int* csr_pad,
                       int M, int N, int G) {
    int i = blockIdx.x * blockDim.x + threadIdx.x;
    if (i < M) ghist[i] = 0;
    if (i < G * 128) pool[i] = 0.f;
    if (i < G) cnt[i] = 0.f;
    if (i < 8) csr_pad[i] = 0;           // 16 ushort pad entries
}

// Per-block LDS histogram of col buckets, flushed to ghist[b*SL + blockIdx&7].
__global__ __launch_bounds__(256) void k_hist(const int* __restrict__ col,
                                              int* __restrict__ ghist,
                                              int E, int C, int NBK) {
    __shared__ int h[784];
    int t = threadIdx.x;
    for (int i = t; i < NBK; i += 256) h[i] = 0;
    __syncthreads();
    const int x = blockIdx.x & (SL - 1);
    int e0 = blockIdx.x * C, e1 = min(E, e0 + C);
    for (int e = e0 + t; e < e1; e += 256) atomicAdd(&h[col[e] >> 6], 1);
    __syncthreads();
    for (int b = t; b < NBK; b += 256) {
        int c = h[b];
        if (c) atomicAdd(&ghist[b * SL + x], c);
    }
}

// Exclusive scan of ghist[0..M) -> gbase & cur; sentinel gbase[M]=E; rowptr[N]=E.
__global__ __launch_bounds__(256) void k_bscan(const int* __restrict__ ghist,
                                               int* __restrict__ gbase,
                                               int* __restrict__ cur,
                                               int* __restrict__ rowptr,
                                               int M, int N, int E) {
    __shared__ int ws[4];
    __shared__ int s_carry;
    int t = threadIdx.x, lane = t & 63, wv = t >> 6;
    if (t == 0) s_carry = 0;
    __syncthreads();
    for (int base = 0; base < M; base += 256) {
        int i = base + t;
        int v = (i < M) ? ghist[i] : 0;
        int x = v;
        #pragma unroll
        for (int off = 1; off < 64; off <<= 1) {
            int u = __shfl_up(x, off, 64);
            if (lane >= off) x += u;
        }
        if (lane == 63) ws[wv] = x;
        __syncthreads();
        int woff = 0;
        for (int w = 0; w < wv; ++w) woff += ws[w];
        int excl = s_carry + woff + (x - v);
        if (i < M) { gbase[i] = excl; cur[i] = excl; }
        __syncthreads();
        if (t == 255) s_carry = excl + v;
        __syncthreads();
    }
    if (t == 0) { gbase[M] = E; rowptr[N] = E; }
}

// Append packed (src | coloff<<16) to the (bucket, slice) region. Same edge
// partition as k_hist so region sizes are exact.
__global__ __launch_bounds__(256) void k_bin(const int* __restrict__ row,
                                             const int* __restrict__ col,
                                             int* __restrict__ cur,
                                             unsigned* __restrict__ gbin,
                                             int E, int C) {
    const int x = blockIdx.x & (SL - 1);
    int e0 = blockIdx.x * C, e1 = min(E, e0 + C);
    for (int e = e0 + threadIdx.x; e < e1; e += 256) {
        int c = col[e];
        int si = (c >> 6) * SL + x;
        int pos = atomicAdd(&cur[si], 1);
        gbin[pos] = (unsigned)row[e] | ((unsigned)(c & 63) << 16);
    }
}

// One block per bucket: LDS histogram of its 64 nodes -> rowptr + dinv,
// then scatter entries to exact CSR positions (2B src) in a dense window.
__global__ __launch_bounds__(256) void k_csr(const unsigned* __restrict__ gbin,
                                             const int* __restrict__ gbase,
                                             int* __restrict__ rowptr,
                                             float* __restrict__ dinv,
                                             unsigned short* __restrict__ csrf,
                                             int N) {
    const int b = blockIdx.x, t = threadIdx.x;
    __shared__ int cnt[64], lcur[64];
    if (t < 64) cnt[t] = 0;
    __syncthreads();
    const int beg = gbase[b * SL], end = gbase[(b + 1) * SL];
    for (int i = beg + t; i < end; i += 256)
        atomicAdd(&cnt[gbin[i] >> 16], 1);
    __syncthreads();
    if (t < 64) {
        int v = cnt[t], x = v;
        #pragma unroll
        for (int off = 1; off < 64; off <<= 1) {
            int u = __shfl_up(x, off, 64);
            if (t >= off) x += u;
        }
        int excl = x - v;
        lcur[t] = excl;
        int node = b * 64 + t;
        if (node < N) {
            rowptr[node] = beg + excl;
            dinv[node] = rsqrtf((float)v + 1.0f);
        }
    }
    __syncthreads();
    for (int i = beg + t; i < end; i += 256) {
        unsigned v = gbin[i];
        int p = atomicAdd(&lcur[v >> 16], 1);
        csrf[beg + p] = (unsigned short)(v & 0xFFFFu);
    }
}

// x fp32 -> bf16 scaled by dinv[node] (8 elems/thread; 16 threads per node)
__global__ void k_castx(const float* __restrict__ x, const float* __restrict__ dinv,
                        unsigned short* __restrict__ xb, int total8) {
    int i = blockIdx.x * blockDim.x + threadIdx.x;
    if (i >= total8) return;
    float d = dinv[i >> 4];
    const float4* s = (const float4*)(x + (size_t)i * 8);
    float4 a = s[0], b = s[1];
    uint4 o;
    o.x = ((unsigned)f2bf(d * a.y) << 16) | f2bf(d * a.x);
    o.y = ((unsigned)f2bf(d * a.w) << 16) | f2bf(d * a.z);
    o.z = ((unsigned)f2bf(d * b.y) << 16) | f2bf(d * b.x);
    o.w = ((unsigned)f2bf(d * b.w) << 16) | f2bf(d * b.z);
    *(uint4*)(xb + (size_t)i * 8) = o;
}

// gcn_W (3,128,128) fp32 -> bf16, pre-swizzled 16B chunks.
__global__ void k_wcast(const float* __restrict__ gcnW, uint4* __restrict__ Wb) {
    int cid = blockIdx.x * 256 + threadIdx.x;   // 6144 chunks
    if (cid >= 3 * 2048) return;
    int l = cid >> 11, rem = cid & 2047;
    int o = rem >> 4, c = rem & 15;
    const float4* s = (const float4*)(gcnW + (size_t)l * 16384 + o * 128 + c * 8);
    float4 a = s[0], b = s[1];
    uint4 v;
    v.x = ((unsigned)f2bf(a.y) << 16) | f2bf(a.x);
    v.y = ((unsigned)f2bf(a.w) << 16) | f2bf(a.z);
    v.z = ((unsigned)f2bf(b.y) << 16) | f2bf(b.x);
    v.w = ((unsigned)f2bf(b.w) << 16) | f2bf(b.z);
    Wb[(l << 11) | (o << 4) | (c ^ (o & 15))] = v;
}

// y[n] = dinv[n] * (sum_src h'[src] + h'[n])   (h', y bf16)
// One wave per node, 4/block. 16 fg (16B = 8 bf16) x 4 neighbor slots.
__global__ __launch_bounds__(256) void k_agg(const unsigned short* __restrict__ h,
                                             unsigned short* __restrict__ y,
                                             const float* __restrict__ dinv,
                                             const int* __restrict__ rowptr,
                                             const unsigned short* __restrict__ csrf,
                                             int N) {
    const int lane = threadIdx.x & 63;
    const int n = blockIdx.x * 4 + (threadIdx.x >> 6);
    if (n >= N) return;
    const int fg = lane & 15;
    const int slot = lane >> 4;
    const int s = rowptr[n], e = rowptr[n + 1];

    float acc[8] = {0.f, 0.f, 0.f, 0.f, 0.f, 0.f, 0.f, 0.f};
    for (int base = s; base < e; base += 16) {
        int src_l = csrf[base + fg];               // padded: in-bounds
        #pragma unroll
        for (int i = 0; i < 4; ++i) {
            int j = i * 4 + slot;
            int src = __shfl(src_l, j, 16);
            uint4 v = *(const uint4*)(h + (size_t)src * 128 + fg * 8);
            bool ok = (base + j) < e;              // cndmask, no branch on load
            v.x = ok ? v.x : 0u; v.y = ok ? v.y : 0u;
            v.z = ok ? v.z : 0u; v.w = ok ? v.w : 0u;
            acc[0] += bflo(v.x); acc[1] += bfhi(v.x);
            acc[2] += bflo(v.y); acc[3] += bfhi(v.y);
            acc[4] += bflo(v.z); acc[5] += bfhi(v.z);
            acc[6] += bflo(v.w); acc[7] += bfhi(v.w);
        }
    }
    #pragma unroll
    for (int r = 0; r < 8; ++r) {
        acc[r] += __shfl_xor(acc[r], 16, 64);
        acc[r] += __shfl_xor(acc[r], 32, 64);
    }
    if (slot == 0) {
        float dn = dinv[n];
        uint4 hv = *(const uint4*)(h + (size_t)n * 128 + fg * 8);
        float sv[8] = {bflo(hv.x), bfhi(hv.x), bflo(hv.y), bfhi(hv.y),
                       bflo(hv.z), bfhi(hv.z), bflo(hv.w), bfhi(hv.w)};
        unsigned short ob[8];
        #pragma unroll
        for (int r = 0; r < 8; ++r) ob[r] = f2bf(dn * (acc[r] + sv[r]));
        uint4 o;
        o.x = ((unsigned)ob[1] << 16) | ob[0];
        o.y = ((unsigned)ob[3] << 16) | ob[2];
        o.z = ((unsigned)ob[5] << 16) | ob[4];
        o.w = ((unsigned)ob[7] << 16) | ob[6];
        *(uint4*)(y + (size_t)n * 128 + fg * 8) = o;
    }
}

// C[N,128] = relu(A @ W^T + b) [* dscale[row] if dscale] in bf16 via MFMA.
__global__ __launch_bounds__(256) void k_mm(const unsigned short* __restrict__ A,
                                            const uint4* __restrict__ Wb,
                                            const float* __restrict__ bias,
                                            const float* __restrict__ dscale,
                                            unsigned short* __restrict__ C, int N) {
    __shared__ uint4 Wsh[2048];   // 32 KB, swizzled [o][c^(o&15)]
    const int tid = threadIdx.x;
    #pragma unroll
    for (int it = 0; it < 8; ++it)
        Wsh[tid + it * 256] = Wb[tid + it * 256];

    const int lane = tid & 63;
    const int wv = tid >> 6;
    const int l15 = lane & 15, quad = lane >> 4;
    const int arow_i = blockIdx.x * 64 + wv * 16 + l15;
    const unsigned short* arow = A + (size_t)min(arow_i, N - 1) * 128;

    f32x4 acc[8];
    #pragma unroll
    for (int ct = 0; ct < 8; ++ct) acc[ct] = (f32x4){0.f, 0.f, 0.f, 0.f};

    __syncthreads();
    #pragma unroll
    for (int kiter = 0; kiter < 4; ++kiter) {
        short8 af = *(const short8*)(arow + kiter * 32 + quad * 8);
        const int cswz = (kiter * 4 + quad) ^ l15;
        #pragma unroll
        for (int ct = 0; ct < 8; ++ct) {
            short8 bf = *(const short8*)(&Wsh[((ct * 16 + l15) << 4) | cswz]);
            acc[ct] = __builtin_amdgcn_mfma_f32_16x16x32_bf16(af, bf, acc[ct], 0, 0, 0);
        }
    }

    const int rbase = blockIdx.x * 64 + wv * 16 + quad * 4;
    float ds[4];
    #pragma unroll
    for (int r = 0; r < 4; ++r) {
        int rr = rbase + r;
        ds[r] = (dscale && rr < N) ? dscale[rr] : 1.f;
    }
    #pragma unroll
    for (int ct = 0; ct < 8; ++ct) {
        int colc = ct * 16 + l15;
        float bcol = bias[colc];
        #pragma unroll
        for (int r = 0; r < 4; ++r) {
            int rr = rbase + r;
            if (rr < N) {
                float v = fmaxf(acc[ct][r] + bcol, 0.f) * ds[r];
                C[(size_t)rr * 128 + colc] = f2bf(v);
            }
        }
    }
}

// Mean-pool accumulate (batch sorted), bf16 input, fp32 atomics out.
__global__ __launch_bounds__(256) void k_pool(const unsigned short* __restrict__ h,
                                              const int* __restrict__ batch,
                                              float* __restrict__ pool,
                                              float* __restrict__ cnt, int N) {
    int t = threadIdx.x;
    int fg = t & 15, sg = t >> 4;
    int n0 = blockIdx.x * 512 + sg * 32;
    if (n0 >= N) return;
    int n1 = min(n0 + 32, N);
    int gprev = batch[n0];
    float racc[8] = {0.f, 0.f, 0.f, 0.f, 0.f, 0.f, 0.f, 0.f};
    float rcnt = 0.f;
    for (int n = n0; n < n1; ++n) {
        int g = batch[n];
        if (g != gprev) {
            float* dst = pool + (size_t)gprev * 128 + fg * 8;
            #pragma unroll
            for (int r = 0; r < 8; ++r) atomicAdd(dst + r, racc[r]);
            if (fg == 0) atomicAdd(&cnt[gprev], rcnt);
            #pragma unroll
            for (int r = 0; r < 8; ++r) racc[r] = 0.f;
            rcnt = 0.f; gprev = g;
        }
        uint4 v = *(const uint4*)(h + (size_t)n * 128 + fg * 8);
        racc[0] += bflo(v.x); racc[1] += bfhi(v.x);
        racc[2] += bflo(v.y); racc[3] += bfhi(v.y);
        racc[4] += bflo(v.z); racc[5] += bfhi(v.z);
        racc[6] += bflo(v.w); racc[7] += bfhi(v.w);
        rcnt += 1.f;
    }
    float* dst = pool + (size_t)gprev * 128 + fg * 8;
    #pragma unroll
    for (int r = 0; r < 8; ++r) atomicAdd(dst + r, racc[r]);
    if (fg == 0) atomicAdd(&cnt[gprev], rcnt);
}

// Fused head (fp32). gcn branch: mean -> gcn_out linear (moved after pooling).
__global__ __launch_bounds__(256) void k_head(
    const float* __restrict__ pool, const float* __restrict__ cnt,
    const float* __restrict__ gcnoW, const float* __restrict__ gcnob,
    const float* __restrict__ mol,
    const float* __restrict__ mlpW, const float* __restrict__ mlpb,
    const float* __restrict__ mloW, const float* __restrict__ mlob,
    const float* __restrict__ pW1, const float* __restrict__ pb1,
    const float* __restrict__ pW2, const float* __restrict__ pb2,
    const float* __restrict__ oW, const float* __restrict__ ob,
    float* __restrict__ out) {
    int g = blockIdx.x, t = threadIdx.x;
    __shared__ float s0[256], s1[256], s2[192], mean[128], red[256];

    s0[t] = mol[(size_t)g * 256 + t];
    if (t < 128) {
        float c = cnt[g];
        mean[t] = pool[(size_t)g * 128 + t] / fmaxf(c, 1.f);
    }
    __syncthreads();

    float acc = mlpb[t];
    {
        const float4* w = (const float4*)(mlpW + (size_t)t * 256);
        #pragma unroll 4
        for (int k4 = 0; k4 < 64; ++k4) {
            float4 wv = w[k4];
            acc += s0[k4*4+0]*wv.x + s0[k4*4+1]*wv.y + s0[k4*4+2]*wv.z + s0[k4*4+3]*wv.w;
        }
    }
    s1[t] = fmaxf(acc, 0.f);
    __syncthreads();

    acc = mlpb[256 + t];
    {
        const float4* w = (const float4*)(mlpW + 65536 + (size_t)t * 256);
        #pragma unroll 4
        for (int k4 = 0; k4 < 64; ++k4) {
            float4 wv = w[k4];
            acc += s1[k4*4+0]*wv.x + s1[k4*4+1]*wv.y + s1[k4*4+2]*wv.z + s1[k4*4+3]*wv.w;
        }
    }
    s0[t] = fmaxf(acc, 0.f);
    __syncthreads();

    if (t < 64) {
        float a2 = mlob[t];
        const float4* w = (const float4*)(mloW + (size_t)t * 256);
        #pragma unroll 4
        for (int k4 = 0; k4 < 64; ++k4) {
            float4 wv = w[k4];
            a2 += s0[k4*4+0]*wv.x + s0[k4*4+1]*wv.y + s0[k4*4+2]*wv.z + s0[k4*4+3]*wv.w;
        }
        s2[128 + t] = fmaxf(a2, 0.f);
    } else if (t < 192) {
        int o = t - 64;
        float a2 = gcnob[o];
        const float4* w = (const float4*)(gcnoW + (size_t)o * 128);
        #pragma unroll 4
        for (int k4 = 0; k4 < 32; ++k4) {
            float4 wv = w[k4];
            a2 += mean[k4*4+0]*wv.x + mean[k4*4+1]*wv.y + mean[k4*4+2]*wv.z + mean[k4*4+3]*wv.w;
        }
        s2[o] = a2;   // no relu on gcn_out
    }
    __syncthreads();

    acc = pb1[t];
    {
        const float4* w = (const float4*)(pW1 + (size_t)t * 192);
        #pragma unroll 4
        for (int k4 = 0; k4 < 48; ++k4) {
            float4 wv = w[k4];
            acc += s2[k4*4+0]*wv.x + s2[k4*4+1]*wv.y + s2[k4*4+2]*wv.z + s2[k4*4+3]*wv.w;
        }
    }
    s1[t] = fmaxf(acc, 0.f);
    __syncthreads();

    acc = pb2[t];
    {
        const float4* w = (const float4*)(pW2 + (size_t)t * 256);
        #pragma unroll 4
        for (int k4 = 0; k4 < 64; ++k4) {
            float4 wv = w[k4];
            acc += s1[k4*4+0]*wv.x + s1[k4*4+1]*wv.y + s1[k4*4+2]*wv.z + s1[k4*4+3]*wv.w;
        }
    }
    s0[t] = fmaxf(acc, 0.f);
    __syncthreads();

    red[t] = s0[t] * oW[t];
    __syncthreads();
    for (int off = 128; off > 0; off >>= 1) {
        if (t < off) red[t] += red[t + off];
        __syncthreads();
    }
    if (t == 0) out[g] = red[0] + ob[0];
}

extern "C" void kernel_launch(void* const* d_in, const int* in_sizes, int n_in,
                              void* d_out, int out_size, void* d_ws, size_t ws_size,
                              hipStream_t stream) {
    const float* x     = (const float*)d_in[0];
    const int*   ei    = (const int*)d_in[1];
    const int*   batch = (const int*)d_in[2];
    const float* mol   = (const float*)d_in[3];
    const float* gcnW  = (const float*)d_in[4];
    const float* gcnb  = (const float*)d_in[5];
    const float* gcnoW = (const float*)d_in[6];
    const float* gcnob = (const float*)d_in[7];
    const float* mlpW  = (const float*)d_in[8];
    const float* mlpb  = (const float*)d_in[9];
    const float* mloW  = (const float*)d_in[10];
    const float* mlob  = (const float*)d_in[11];
    const float* pW1   = (const float*)d_in[12];
    const float* pb1   = (const float*)d_in[13];
    const float* pW2   = (const float*)d_in[14];
    const float* pb2   = (const float*)d_in[15];
    const float* oW    = (const float*)d_in[16];
    const float* ob    = (const float*)d_in[17];

    const int N = in_sizes[0] / 128;
    const int E = in_sizes[1] / 2;
    const int G = in_sizes[3] / 256;
    const int* row = ei;
    const int* col = ei + E;

    const int NBK = (N + BKT - 1) / BKT;       // 782 buckets
    const int M = NBK * SL;                    // 6256 (bucket, slice) cells
    const int C = (E + NBINBLK - 1) / NBINBLK; // edges per bin block

    char* p = (char*)d_ws;
    auto alloc = [&](size_t bytes) {
        char* q = p;
        p += (bytes + 255) & ~(size_t)255;
        return (void*)q;
    };
    int*    rowptr = (int*)alloc((size_t)(N + 1) * 4);
    float*  dinv   = (float*)alloc((size_t)N * 4);
    int*    ghist  = (int*)alloc((size_t)M * 4);
    int*    gbase  = (int*)alloc((size_t)(M + 1) * 4);
    int*    cur    = (int*)alloc((size_t)M * 4);
    unsigned* gbin = (unsigned*)alloc((size_t)E * 4);
    unsigned short* csrf = (unsigned short*)alloc((size_t)(E + 16) * 2);
    unsigned short* xb   = (unsigned short*)alloc((size_t)N * 128 * 2);
    unsigned short* bufA = (unsigned short*)alloc((size_t)N * 128 * 2);
    unsigned short* bufB = (unsigned short*)alloc((size_t)N * 128 * 2);
    uint4*  Wb     = (uint4*)alloc((size_t)3 * 2048 * 16);
    float*  pool   = (float*)alloc((size_t)G * 128 * 4);
    float*  cnt    = (float*)alloc((size_t)G * 4);

    const int NB = (N + 255) / 256;

    k_zero<<<NB, 256, 0, stream>>>(ghist, pool, cnt, (int*)(csrf + E), M, N, G);
    k_wcast<<<24, 256, 0, stream>>>(gcnW, Wb);
    k_hist<<<NBINBLK, 256, 0, stream>>>(col, ghist, E, C, NBK);
    k_bscan<<<1, 256, 0, stream>>>(ghist, gbase, cur, rowptr, M, N, E);
    k_bin<<<NBINBLK, 256, 0, stream>>>(row, col, cur, gbin, E, C);
    k_csr<<<NBK, 256, 0, stream>>>(gbin, gbase, rowptr, dinv, csrf, N);
    k_castx<<<(N * 16 + 255) / 256, 256, 0, stream>>>(x, dinv, xb, N * 16);

    const int mmblocks = (N + 63) / 64;
    const int aggblocks = (N + 3) / 4;
    const unsigned short* src = xb;
    for (int l = 0; l < 3; ++l) {
        k_agg<<<aggblocks, 256, 0, stream>>>(src, bufA, dinv, rowptr, csrf, N);
        k_mm<<<mmblocks, 256, 0, stream>>>(bufA, Wb + (size_t)l * 2048,
                                           gcnb + (size_t)l * 128,
                                           (l < 2) ? dinv : (const float*)nullptr,
                                           bufB, N);
        src = bufB;
    }
    k_pool<<<(N + 511) / 512, 256, 0, stream>>>(bufB, batch, pool, cnt, N);
    k_head<<<G, 256, 0, stream>>>(pool, cnt, gcnoW, gcnob, mol, mlpW, mlpb,
                                  mloW, mlob, pW1, pb1, pW2, pb2, oW, ob,
                                  (float*)d_out);
}